// Round 4
// baseline (554.994 us; speedup 1.0000x reference)
//
#include <hip/hip_runtime.h>
#include <hip/hip_bf16.h>

// UnifiedMambaBlock: B=2, L=1024, D_MODEL=2048, D_INNER=4096, N_STATE=16,
// DT_RANK=128, D_CONV=4.  ALL inputs/outputs fp32 (per reference dtypes).
// bf16 MFMA compute (no fp32 MFMA on CDNA4); fp32 epilogues.
//
// R11: scan restructured to packed-FP32 (v_pk_*): 8 lanes/channel, each lane
// owns states (n0, n0+8) as an f32x2 h-pair.  Per-lane per-step instruction
// count now covers 2 elements (pk mul/fma + 2 scalar exp2), and the DPP
// reduction tree shrinks 4->3 levels (8-lane).  Grid: 256 blocks x 256 thr
// (32 channels/block).  DPP stays on the builtin (R9 hazard lesson).
// R10: z-gate silu(z) precomputed in conv kernel; conv vectorized.
// R8: in_proj GEMM = 256x256 deep-pipelined schedule (counted vmcnt, T2
// swizzle via pre-swizzled global source, T5 setprio, T1 XCD swizzle).

#define DEV __device__ __forceinline__

typedef __attribute__((ext_vector_type(8))) __bf16 bf16x8;
typedef __attribute__((ext_vector_type(4))) float f32x4;
typedef __attribute__((ext_vector_type(2))) float f32x2;
typedef unsigned int u32;

DEV float bf2f(__hip_bfloat16 x) { return __bfloat162float(x); }
DEV __hip_bfloat16 f2bf(float x) { return __float2bfloat16(x); }
DEV float bfu2f(unsigned short u) {
    union { u32 i; float f; } c; c.i = ((u32)u) << 16; return c.f;
}
DEV unsigned short f2bfu(float x) {
    __hip_bfloat16 h = __float2bfloat16(x);
    return *reinterpret_cast<unsigned short*>(&h);
}
DEV float softplusf(float v) { return v > 20.f ? v : log1pf(__expf(v)); }
DEV float siluf(float v) { return v / (1.f + __expf(-v)); }

DEV void storeOut(float* C, size_t off, float v) { C[off] = v; }
DEV void storeOut(__hip_bfloat16* C, size_t off, float v) { C[off] = f2bf(v); }

// async 16B global -> LDS (global_load_lds_dwordx4).
// LDS destination must be wave-uniform base + lane*16 (HW constraint).
DEV void async16(void* lds, const void* g) {
    __builtin_amdgcn_global_load_lds(
        (const __attribute__((address_space(1))) u32*)(unsigned long long)g,
        (__attribute__((address_space(3))) u32*)(u32)(unsigned long long)lds,
        16, 0, 0);
}

// DPP-based add of lane (permuted) value; reduction over lane groups.
// MUST stay as the builtin: compiler inserts required DPP hazard nops.
template <int CTRL>
DEV float dppadd(float v) {
    int x = __builtin_amdgcn_update_dpp(
        0, __builtin_bit_cast(int, v), CTRL, 0xF, 0xF, true);
    return v + __builtin_bit_cast(float, x);
}

// ---------------------------------------------------------------------------
// 256x256-tile deep-pipelined GEMM: C = A @ W^T + bias (bf16 in, bf16 out).
// 512 threads = 8 waves (2M x 4N), per-wave 128x64 output, BK=32.
// 4 LDS buffers, prefetch distance 3 tiles, counted vmcnt, T2 swizzle, T5.
// Requires: M%256==0, N%256==0, K%32==0 (K>=96 for full pipeline benefit).
// ---------------------------------------------------------------------------
__global__ __launch_bounds__(512, 2) void gemm256_bt(
    const __hip_bfloat16* __restrict__ A, int lda,
    const __hip_bfloat16* __restrict__ W, int ldw,
    const float* __restrict__ bias,
    __hip_bfloat16* __restrict__ C, int ldc, int K)
{
    __shared__ __align__(16) unsigned short As[4][256 * 32];  // 64 KB
    __shared__ __align__(16) unsigned short Bs[4][256 * 32];  // 64 KB

    const int t    = threadIdx.x;
    // T1: bijective XCD swizzle (nwg % 8 == 0 guaranteed by launch shapes)
    const int nwg  = gridDim.x * gridDim.y;
    const int orig = blockIdx.y * gridDim.x + blockIdx.x;
    const int swz  = (orig & 7) * (nwg >> 3) + (orig >> 3);
    const int mBase = (swz / gridDim.x) * 256;
    const int nBase = (swz % gridDim.x) * 256;

    const int wave = t >> 6;
    const int lane = t & 63;
    const int wm   = (wave >> 2) * 128;   // 2 M wave-groups
    const int wn   = (wave & 3) * 64;     // 4 N wave-groups
    const int ln15 = lane & 15;
    const int quad = lane >> 4;
    const int kof  = quad * 8;

    f32x4 acc[8][4];
    const f32x4 vzero = {0.f, 0.f, 0.f, 0.f};
#pragma unroll
    for (int i = 0; i < 8; ++i)
#pragma unroll
        for (int j = 0; j < 4; ++j) acc[i][j] = vzero;

    // Stage one half-tile (rows half*128..half*128+127) of A and B of a
    // K-tile into buffer buf.  LDS dest is linear (HW constraint of
    // global_load_lds); the T2 swizzle is applied by INVERSE-swizzling the
    // global source address (rule #21).
    auto stage = [&](int buf, int k0, int half) {
        const int idx = half * 512 + t;                 // 0..1023 -> 16B slot
        const int le  = (idx * 8) ^ (((idx >> 3) & 3) << 3);
        const int r   = le >> 5;
        const int c   = le & 31;
        async16(&As[buf][idx * 8], A + (size_t)(mBase + r) * lda + k0 + c);
        async16(&Bs[buf][idx * 8], W + (size_t)(nBase + r) * ldw + k0 + c);
    };

    const int NT = K >> 5;

#pragma unroll 1
    for (int p = 0; p < 3 && p < NT; ++p) {
        stage(p, p << 5, 0);
        stage(p, p << 5, 1);
    }

#pragma unroll 1
    for (int T = 0; T < NT; ++T) {
        const int buf = T & 3;
        if (T + 2 < NT)      asm volatile("s_waitcnt vmcnt(8)" ::: "memory");
        else if (T + 1 < NT) asm volatile("s_waitcnt vmcnt(4)" ::: "memory");
        else                 asm volatile("s_waitcnt vmcnt(0)" ::: "memory");
        __builtin_amdgcn_s_barrier();          // all waves' vmcnt passed
        __builtin_amdgcn_sched_barrier(0);     // no ds_read hoists above

        const unsigned short* __restrict__ Ab = As[buf];
        const unsigned short* __restrict__ Bb = Bs[buf];
        const int k0n  = (T + 3) << 5;
        const int bufn = (T + 3) & 3;          // != buf; == (T-1)&3 (dead)

        // ---- phase 1: A-frags 0-3 + all B-frags, 16 MFMA ----
        bf16x8 af[4], bfr[4], af2[4];
#pragma unroll
        for (int i = 0; i < 4; ++i) {
            const int ra = wm + i * 16 + ln15;
            af[i] = *reinterpret_cast<const bf16x8*>(
                &Ab[(ra * 32 + kof) ^ (((ra >> 1) & 3) << 3)]);
            const int rb = wn + i * 16 + ln15;
            bfr[i] = *reinterpret_cast<const bf16x8*>(
                &Bb[(rb * 32 + kof) ^ (((rb >> 1) & 3) << 3)]);
        }
        if (T + 3 < NT) stage(bufn, k0n, 0);
        __builtin_amdgcn_s_barrier();
        __builtin_amdgcn_s_setprio(1);
#pragma unroll
        for (int i = 0; i < 4; ++i)
#pragma unroll
            for (int j = 0; j < 4; ++j)
                acc[i][j] = __builtin_amdgcn_mfma_f32_16x16x32_bf16(
                    af[i], bfr[j], acc[i][j], 0, 0, 0);
        __builtin_amdgcn_s_setprio(0);
        __builtin_amdgcn_sched_barrier(0);

        // ---- phase 2: A-frags 4-7 (reuse B-frags), 16 MFMA ----
#pragma unroll
        for (int i = 0; i < 4; ++i) {
            const int ra = wm + 64 + i * 16 + ln15;
            af2[i] = *reinterpret_cast<const bf16x8*>(
                &Ab[(ra * 32 + kof) ^ (((ra >> 1) & 3) << 3)]);
        }
        if (T + 3 < NT) stage(bufn, k0n, 1);
        __builtin_amdgcn_s_barrier();
        __builtin_amdgcn_s_setprio(1);
#pragma unroll
        for (int i = 0; i < 4; ++i)
#pragma unroll
            for (int j = 0; j < 4; ++j)
                acc[4 + i][j] = __builtin_amdgcn_mfma_f32_16x16x32_bf16(
                    af2[i], bfr[j], acc[4 + i][j], 0, 0, 0);
        __builtin_amdgcn_s_setprio(0);
        __builtin_amdgcn_sched_barrier(0);
    }

    // epilogue: C/D layout col = lane&15, row = quad*4 + reg
#pragma unroll
    for (int i = 0; i < 8; ++i) {
        const int gm = mBase + wm + i * 16 + quad * 4;
#pragma unroll
        for (int j = 0; j < 4; ++j) {
            const int gn = nBase + wn + j * 16 + ln15;
            const float bv = bias ? bias[gn] : 0.f;
#pragma unroll
            for (int r = 0; r < 4; ++r)
                C[(size_t)(gm + r) * ldc + gn] = f2bf(acc[i][j][r] + bv);
        }
    }
}

// ---------------------------------------------------------------------------
// C = A @ W^T + bias GEMM, bf16 inputs, DOUBLE-BUFFERED async LDS staging.
// Block tile 128x128, BK=64, 256 threads = 4 waves 2x2, wave does 64x64 via
// 4x4 frags of mfma_f32_16x16x32_bf16.
// Requires: M%128==0, N%128==0, K%64==0, lda/ldw mult of 8.
// ---------------------------------------------------------------------------
template <int ACT, typename OutT>
__global__ __launch_bounds__(256) void gemm_bt(
    const __hip_bfloat16* __restrict__ A, int lda,
    const __hip_bfloat16* __restrict__ W, int ldw,
    const float* __restrict__ bias,
    OutT* __restrict__ C, int ldc, int K)
{
    __shared__ __align__(16) unsigned short AsU[2][128 * 64];
    __shared__ __align__(16) unsigned short BsU[2][128 * 64];

    const int t     = threadIdx.x;
    const int mBase = blockIdx.y * 128;
    const int nBase = blockIdx.x * 128;
    const int wave  = t >> 6;
    const int lane  = t & 63;
    const int wm    = (wave >> 1) * 64;
    const int wn    = (wave & 1) * 64;
    const int ln15  = lane & 15;
    const int quad  = lane >> 4;

    f32x4 acc[4][4];
    const f32x4 vzero = {0.f, 0.f, 0.f, 0.f};
#pragma unroll
    for (int i = 0; i < 4; ++i)
#pragma unroll
        for (int j = 0; j < 4; ++j) acc[i][j] = vzero;

    auto stage = [&](int buf, int k0) {
#pragma unroll
        for (int i = 0; i < 4; ++i) {
            int idx = i * 256 + t;
            int r = idx >> 3;
            int c = (idx & 7) << 3;
            async16(&AsU[buf][idx * 8], A + (size_t)(mBase + r) * lda + k0 + c);
            async16(&BsU[buf][idx * 8], W + (size_t)(nBase + r) * ldw + k0 + c);
        }
    };

    const int nIter = K >> 6;
    stage(0, 0);

    for (int it = 0; it < nIter; ++it) {
        __syncthreads();   // buf[it&1] resident; prior reads of other buf done
        if (it + 1 < nIter) stage((it + 1) & 1, (it + 1) << 6);
        const unsigned short* As = AsU[it & 1];
        const unsigned short* Bs = BsU[it & 1];

#pragma unroll
        for (int kk = 0; kk < 64; kk += 32) {
            const int kof = kk + quad * 8;
            bf16x8 af[4], bfr[4];
#pragma unroll
            for (int i = 0; i < 4; ++i) {
                af[i]  = *reinterpret_cast<const bf16x8*>(&As[(wm + i * 16 + ln15) * 64 + kof]);
                bfr[i] = *reinterpret_cast<const bf16x8*>(&Bs[(wn + i * 16 + ln15) * 64 + kof]);
            }
#pragma unroll
            for (int i = 0; i < 4; ++i)
#pragma unroll
                for (int j = 0; j < 4; ++j)
                    acc[i][j] = __builtin_amdgcn_mfma_f32_16x16x32_bf16(af[i], bfr[j], acc[i][j], 0, 0, 0);
        }
    }

    // epilogue: C/D layout col = lane&15, row = quad*4 + reg
#pragma unroll
    for (int i = 0; i < 4; ++i) {
        const int gm = mBase + wm + i * 16 + quad * 4;
#pragma unroll
        for (int j = 0; j < 4; ++j) {
            const int gn = nBase + wn + j * 16 + ln15;
            const float bv = bias ? bias[gn] : 0.f;
#pragma unroll
            for (int r = 0; r < 4; ++r) {
                float v = acc[i][j][r] + bv;
                if (ACT == 1) v = softplusf(v);
                storeOut(C, (size_t)(gm + r) * ldc + gn, v);
            }
        }
    }
}

// ---------------------------------------------------------------------------
// Split-K variant: grid (nx, ny, SLICES); slice z handles K-range
// [z*K/SLICES, (z+1)*K/SLICES), stores fp32 partial at part + z*sliceElems.
// ---------------------------------------------------------------------------
__global__ __launch_bounds__(256) void gemm_bt_sk(
    const __hip_bfloat16* __restrict__ A, int lda,
    const __hip_bfloat16* __restrict__ W, int ldw,
    float* __restrict__ part, int ldc, int K, int slices, int sliceElems)
{
    __shared__ __align__(16) unsigned short AsU[2][128 * 64];
    __shared__ __align__(16) unsigned short BsU[2][128 * 64];

    const int t     = threadIdx.x;
    const int mBase = blockIdx.y * 128;
    const int nBase = blockIdx.x * 128;
    const int kLen  = K / slices;
    const int kOff  = blockIdx.z * kLen;
    const int wave  = t >> 6;
    const int lane  = t & 63;
    const int wm    = (wave >> 1) * 64;
    const int wn    = (wave & 1) * 64;
    const int ln15  = lane & 15;
    const int quad  = lane >> 4;

    f32x4 acc[4][4];
    const f32x4 vzero = {0.f, 0.f, 0.f, 0.f};
#pragma unroll
    for (int i = 0; i < 4; ++i)
#pragma unroll
        for (int j = 0; j < 4; ++j) acc[i][j] = vzero;

    auto stage = [&](int buf, int k0) {
#pragma unroll
        for (int i = 0; i < 4; ++i) {
            int idx = i * 256 + t;
            int r = idx >> 3;
            int c = (idx & 7) << 3;
            async16(&AsU[buf][idx * 8], A + (size_t)(mBase + r) * lda + k0 + c);
            async16(&BsU[buf][idx * 8], W + (size_t)(nBase + r) * ldw + k0 + c);
        }
    };

    const int nIter = kLen >> 6;
    stage(0, kOff);

    for (int it = 0; it < nIter; ++it) {
        __syncthreads();
        if (it + 1 < nIter) stage((it + 1) & 1, kOff + ((it + 1) << 6));
        const unsigned short* As = AsU[it & 1];
        const unsigned short* Bs = BsU[it & 1];

#pragma unroll
        for (int kk = 0; kk < 64; kk += 32) {
            const int kof = kk + quad * 8;
            bf16x8 af[4], bfr[4];
#pragma unroll
            for (int i = 0; i < 4; ++i) {
                af[i]  = *reinterpret_cast<const bf16x8*>(&As[(wm + i * 16 + ln15) * 64 + kof]);
                bfr[i] = *reinterpret_cast<const bf16x8*>(&Bs[(wn + i * 16 + ln15) * 64 + kof]);
            }
#pragma unroll
            for (int i = 0; i < 4; ++i)
#pragma unroll
                for (int j = 0; j < 4; ++j)
                    acc[i][j] = __builtin_amdgcn_mfma_f32_16x16x32_bf16(af[i], bfr[j], acc[i][j], 0, 0, 0);
        }
    }

    float* Cp = part + (size_t)blockIdx.z * sliceElems;
#pragma unroll
    for (int i = 0; i < 4; ++i) {
        const int gm = mBase + wm + i * 16 + quad * 4;
#pragma unroll
        for (int j = 0; j < 4; ++j) {
            const int gn = nBase + wn + j * 16 + ln15;
#pragma unroll
            for (int r = 0; r < 4; ++r)
                Cp[(size_t)(gm + r) * ldc + gn] = acc[i][j][r];
        }
    }
}

// sum 8 fp32 partials -> bf16 proj.  total = 2048*256 elems.
__global__ __launch_bounds__(256) void reduce_proj(
    const float* __restrict__ part, __hip_bfloat16* __restrict__ proj)
{
    int i = blockIdx.x * 256 + threadIdx.x;
    float s = 0.f;
#pragma unroll
    for (int z = 0; z < 8; ++z) s += part[(size_t)z * 524288 + i];
    proj[i] = f2bf(s);
}

// ---------------------------------------------------------------------------
// fp32 -> bf16 cast, 8 elems/thread.  n must be a multiple of 2048.
// ---------------------------------------------------------------------------
__global__ __launch_bounds__(256) void cast_f32_bf16(
    const float* __restrict__ in, __hip_bfloat16* __restrict__ out)
{
    size_t i = ((size_t)blockIdx.x * 256 + threadIdx.x) * 8;
    const float4 a = *reinterpret_cast<const float4*>(in + i);
    const float4 b = *reinterpret_cast<const float4*>(in + i + 4);
    unsigned short r[8];
    r[0] = f2bfu(a.x); r[1] = f2bfu(a.y); r[2] = f2bfu(a.z); r[3] = f2bfu(a.w);
    r[4] = f2bfu(b.x); r[5] = f2bfu(b.y); r[6] = f2bfu(b.z); r[7] = f2bfu(b.w);
    *reinterpret_cast<uint4*>(out + i) = *reinterpret_cast<uint4*>(r);
}

// ---------------------------------------------------------------------------
// wcat bf16 [256,4096]: rows 0..127 w_xdt, 128..143 w_xb, 144..159 w_xc.
// ---------------------------------------------------------------------------
__global__ __launch_bounds__(256) void build_wcat(
    const float* __restrict__ w_xdt,
    const float* __restrict__ w_xb,
    const float* __restrict__ w_xc,
    __hip_bfloat16* __restrict__ wcat)
{
    int tid = blockIdx.x * 256 + threadIdx.x;
    int r = tid >> 12;
    int c = tid & 4095;
    float v = 0.f;
    if (r < 128)      v = w_xdt[r * 4096 + c];
    else if (r < 144) v = w_xb[(r - 128) * 4096 + c];
    else if (r < 160) v = w_xc[(r - 144) * 4096 + c];
    wcat[tid] = f2bf(v);
}

// ---------------------------------------------------------------------------
// Vectorized causal depthwise conv (win 4, left pad 3) + bias + silu over
// xz[:, :4096] -> xc, AND silu over xz[:, 4096:] IN PLACE (z-gate precompute
// for the scan).  8 outputs per thread, uint4 loads/stores.
// Grid: 2^21 threads = 8192 blocks x 256.  First 2^20 threads conv, rest z.
// Conv reads only the x-half; z threads read/write only the z-half -> no
// read/write overlap anywhere.
// ---------------------------------------------------------------------------
__global__ __launch_bounds__(256) void conv_siluz(
    const __hip_bfloat16* __restrict__ xzr,
    __hip_bfloat16* __restrict__ xzw,          // same buffer, z-half writes
    const float* __restrict__ conv_w,
    const float* __restrict__ conv_b,
    __hip_bfloat16* __restrict__ xc)
{
    const int tid = blockIdx.x * 256 + threadIdx.x;
    if (tid < (1 << 20)) {
        const int row = tid >> 9;            // 0..2047 (b*1024 + l)
        const int d8  = (tid & 511) << 3;    // 0..4088 step 8
        const int l   = row & 1023;
        uint4 tv[4];
#pragma unroll
        for (int k = 0; k < 4; ++k) {
            const int ll = l - 3 + k;
            if (ll >= 0)
                tv[k] = *reinterpret_cast<const uint4*>(
                    &xzr[(size_t)(row - 3 + k) * 8192 + d8]);
            else
                tv[k] = make_uint4(0u, 0u, 0u, 0u);   // bf16 zeros
        }
        const float4 b0 = *reinterpret_cast<const float4*>(&conv_b[d8]);
        const float4 b1 = *reinterpret_cast<const float4*>(&conv_b[d8 + 4]);
        const unsigned short* t0 = (const unsigned short*)&tv[0];
        const unsigned short* t1 = (const unsigned short*)&tv[1];
        const unsigned short* t2 = (const unsigned short*)&tv[2];
        const unsigned short* t3 = (const unsigned short*)&tv[3];
        unsigned short o[8];
#pragma unroll
        for (int j = 0; j < 8; ++j) {
            const float4 w = *reinterpret_cast<const float4*>(&conv_w[(d8 + j) * 4]);
            float acc = (j < 4) ? ((const float*)&b0)[j] : ((const float*)&b1)[j - 4];
            acc += bfu2f(t0[j]) * w.x;
            acc += bfu2f(t1[j]) * w.y;
            acc += bfu2f(t2[j]) * w.z;
            acc += bfu2f(t3[j]) * w.w;
            o[j] = f2bfu(siluf(acc));
        }
        *reinterpret_cast<uint4*>(&xc[(size_t)row * 4096 + d8]) =
            *reinterpret_cast<const uint4*>(o);
    } else {
        const int zi  = tid - (1 << 20);
        const int row = zi >> 9;
        const int d8  = (zi & 511) << 3;
        const size_t a = (size_t)row * 8192 + 4096 + d8;
        const uint4 v = *reinterpret_cast<const uint4*>(&xzr[a]);
        const unsigned short* zv = (const unsigned short*)&v;
        unsigned short o[8];
#pragma unroll
        for (int j = 0; j < 8; ++j)
            o[j] = f2bfu(siluf(bfu2f(zv[j])));
        *reinterpret_cast<uint4*>(&xzw[a]) = *reinterpret_cast<const uint4*>(o);
    }
}

// ---------------------------------------------------------------------------
// selective scan, packed-FP32: 8 lanes/channel (n0 = t&7), each lane owns
// states n0 and n0+8 as an f32x2.  32 channels/block, 256 blocks.
// Transposed LDS staging, builtin-DPP 3-level 8-lane reduction, register
// prefetch of the next time-chunk.  z-half of xz holds PRE-GATED silu(z).
// ---------------------------------------------------------------------------
#define SCAN_T 128
#define ST4 132
#define ST2 136

__global__ __launch_bounds__(256) void scan_kernel(
    const float* __restrict__ dt,              // [2048, 4096] fp32
    __hip_bfloat16* xcyg,                      // [2048, 4096] bf16 in/out
    const __hip_bfloat16* __restrict__ proj,   // [2048, 256]; B at 128, C at 144
    const __hip_bfloat16* __restrict__ xz,     // [2048, 8192]; zg at 4096+d
    const float* __restrict__ A_log,           // [4096, 16] fp32
    const float* __restrict__ Dp)              // [4096] fp32
{
    __shared__ __align__(16) float          s_dt[32 * ST4];   // [d][time]
    __shared__ __align__(16) unsigned short s_x [32 * ST2];
    __shared__ __align__(16) unsigned short s_z [32 * ST2];
    __shared__ __align__(16) unsigned short s_B [16 * ST2];   // [state][time]
    __shared__ __align__(16) unsigned short s_C [16 * ST2];
    __shared__ __align__(16) unsigned short s_y [32 * ST2];

    const int t   = threadIdx.x;
    const int g   = t >> 3;          // channel in block, 0..31
    const int n0  = t & 7;           // state pair base (n0, n0+8)
    const int ch0 = blockIdx.x * 32;
    const int b   = ch0 >> 12;
    const int d0  = ch0 & 4095;
    const int d   = d0 + g;

    f32x2 A2;
    A2.x = -__expf(A_log[d * 16 + n0]) * 1.44269504f;
    A2.y = -__expf(A_log[d * 16 + n0 + 8]) * 1.44269504f;
    const float Dpar = Dp[d];
    const size_t rowBase = (size_t)b * 1024;

    // staging thread mappings (128 time-rows per chunk)
    const int rD = t >> 3, cD = (t & 7) << 2;   // dt: rows rD+32i, 4 floats
    const int rX = t >> 2, cX = (t & 3) << 3;   // x/z/y: rows rX+64i, 8 shorts
    const int rB = t >> 1, cB = (t & 1) << 3;   // B/C: row rB, 8 shorts

    float4 rdt[4]; uint4 rx[2], rz[2], rBv, rCv;
    auto load_chunk = [&](int t0) {
#pragma unroll
        for (int i = 0; i < 4; ++i)
            rdt[i] = *reinterpret_cast<const float4*>(
                &dt[(rowBase + t0 + rD + i * 32) * 4096 + d0 + cD]);
#pragma unroll
        for (int i = 0; i < 2; ++i) {
            rx[i] = *reinterpret_cast<const uint4*>(
                &xcyg[(rowBase + t0 + rX + i * 64) * 4096 + d0 + cX]);
            rz[i] = *reinterpret_cast<const uint4*>(
                &xz[(rowBase + t0 + rX + i * 64) * 8192 + 4096 + d0 + cX]);
        }
        rBv = *reinterpret_cast<const uint4*>(
            &proj[(rowBase + t0 + rB) * 256 + 128 + cB]);
        rCv = *reinterpret_cast<const uint4*>(
            &proj[(rowBase + t0 + rB) * 256 + 144 + cB]);
    };

    load_chunk(0);
    f32x2 h = {0.f, 0.f};

    for (int c = 0; c < 1024 / SCAN_T; ++c) {
        const int t0 = c * SCAN_T;
        __syncthreads();
        {
#pragma unroll
            for (int i = 0; i < 4; ++i) {
                const float* p = (const float*)&rdt[i];
#pragma unroll
                for (int jj = 0; jj < 4; ++jj)
                    s_dt[(cD + jj) * ST4 + rD + i * 32] = p[jj];
            }
#pragma unroll
            for (int i = 0; i < 2; ++i) {
                const unsigned short* px = (const unsigned short*)&rx[i];
                const unsigned short* pz = (const unsigned short*)&rz[i];
#pragma unroll
                for (int jj = 0; jj < 8; ++jj) {
                    s_x[(cX + jj) * ST2 + rX + i * 64] = px[jj];
                    s_z[(cX + jj) * ST2 + rX + i * 64] = pz[jj];
                }
            }
            {
                const unsigned short* pB = (const unsigned short*)&rBv;
                const unsigned short* pC = (const unsigned short*)&rCv;
#pragma unroll
                for (int jj = 0; jj < 8; ++jj) {
                    s_B[(cB + jj) * ST2 + rB] = pB[jj];
                    s_C[(cB + jj) * ST2 + rB] = pC[jj];
                }
            }
        }
        __syncthreads();
        if (c + 1 < 1024 / SCAN_T) load_chunk(t0 + SCAN_T);

#pragma unroll 1
        for (int l0 = 0; l0 < SCAN_T; l0 += 8) {
            const float4 vd0 = *reinterpret_cast<const float4*>(&s_dt[g * ST4 + l0]);
            const float4 vd1 = *reinterpret_cast<const float4*>(&s_dt[g * ST4 + l0 + 4]);
            const uint4 vx  = *reinterpret_cast<const uint4*>(&s_x[g * ST2 + l0]);
            const uint4 vz  = *reinterpret_cast<const uint4*>(&s_z[g * ST2 + l0]);
            const uint4 vB0 = *reinterpret_cast<const uint4*>(&s_B[n0 * ST2 + l0]);
            const uint4 vB1 = *reinterpret_cast<const uint4*>(&s_B[(n0 + 8) * ST2 + l0]);
            const uint4 vC0 = *reinterpret_cast<const uint4*>(&s_C[n0 * ST2 + l0]);
            const uint4 vC1 = *reinterpret_cast<const uint4*>(&s_C[(n0 + 8) * ST2 + l0]);
            const unsigned short* ux  = (const unsigned short*)&vx;
            const unsigned short* uz  = (const unsigned short*)&vz;
            const unsigned short* uB0 = (const unsigned short*)&vB0;
            const unsigned short* uB1 = (const unsigned short*)&vB1;
            const unsigned short* uC0 = (const unsigned short*)&vC0;
            const unsigned short* uC1 = (const unsigned short*)&vC1;
            const float* fd0 = (const float*)&vd0;
            const float* fd1 = (const float*)&vd1;
            unsigned short y8[8];
#pragma unroll
            for (int j = 0; j < 8; ++j) {
                const float dtv = (j < 4) ? fd0[j] : fd1[j - 4];
                const float xv  = bfu2f(ux[j]);
                f32x2 Bp; Bp.x = bfu2f(uB0[j]); Bp.y = bfu2f(uB1[j]);
                f32x2 Cp; Cp.x = bfu2f(uC0[j]); Cp.y = bfu2f(uC1[j]);
                const f32x2 dA = A2 * (f32x2){dtv, dtv};
                f32x2 e;
                e.x = __builtin_amdgcn_exp2f(dA.x);
                e.y = __builtin_amdgcn_exp2f(dA.y);
                const float xdt = xv * dtv;
                const f32x2 tt = Bp * (f32x2){xdt, xdt};
                h = __builtin_elementwise_fma(h, e, tt);   // v_pk_fma_f32
                const f32x2 pp = h * Cp;
                float p = pp.x + pp.y;
                p = dppadd<0xB1>(p);    // xor1 within quad
                p = dppadd<0x4E>(p);    // xor2 within quad
                p = dppadd<0x141>(p);   // half-row mirror: combine quads
                if (n0 == 0) {
                    const float zgv = bfu2f(uz[j]);   // pre-gated silu(z)
                    y8[j] = f2bfu((p + Dpar * xv) * zgv);
                }
            }
            if (n0 == 0)
                *reinterpret_cast<uint4*>(&s_y[g * ST2 + l0]) =
                    *reinterpret_cast<const uint4*>(y8);
        }
        __syncthreads();

        {
#pragma unroll
            for (int i = 0; i < 2; ++i) {
                unsigned short tmp[8];
#pragma unroll
                for (int jj = 0; jj < 8; ++jj)
                    tmp[jj] = s_y[(cX + jj) * ST2 + rX + i * 64];
                *reinterpret_cast<uint4*>(
                    &xcyg[(rowBase + t0 + rX + i * 64) * 4096 + d0 + cX]) =
                    *reinterpret_cast<const uint4*>(tmp);
            }
        }
    }
}

// ---------------------------------------------------------------------------
extern "C" void kernel_launch(void* const* d_in, const int* in_sizes, int n_in,
                              void* d_out, int out_size, void* d_ws, size_t ws_size,
                              hipStream_t stream)
{
    const float* u      = (const float*)d_in[0];
    const float* w_in   = (const float*)d_in[1];
    const float* b_in   = (const float*)d_in[2];
    const float* w_out  = (const float*)d_in[3];
    const float* b_out  = (const float*)d_in[4];
    const float* w_dt   = (const float*)d_in[5];
    const float* b_dt   = (const float*)d_in[6];
    const float* w_xdt  = (const float*)d_in[7];
    const float* w_xb   = (const float*)d_in[8];
    const float* w_xc   = (const float*)d_in[9];
    const float* conv_w = (const float*)d_in[10];
    const float* conv_b = (const float*)d_in[11];
    const float* A_log  = (const float*)d_in[12];
    const float* D_par  = (const float*)d_in[13];
    float* out = (float*)d_out;

    char* ws = (char*)d_ws;
    __hip_bfloat16* xz    = (__hip_bfloat16*)(ws);             // [2048,8192] 33.5 MB
    __hip_bfloat16* xc    = (__hip_bfloat16*)(ws + 33554432);  // [2048,4096] 16.8 MB
    __hip_bfloat16* u_bf  = (__hip_bfloat16*)(ws + 33554432);  // dead before xc written
    __hip_bfloat16* wcat  = (__hip_bfloat16*)(ws + 50331648);  // [256,4096]  2.1 MB
    __hip_bfloat16* w_dt_bf = (__hip_bfloat16*)(ws + 50331648);// [4096,128] 1 MB (after wcat dead)
    __hip_bfloat16* proj  = (__hip_bfloat16*)(ws + 52428800);  // [2048,256]  1.0 MB
    float*          dtb   = (float*)(ws + 53477376);           // [2048,4096] 33.5 MB
    __hip_bfloat16* w_in_bf  = (__hip_bfloat16*)(ws + 53477376); // dead before dtb written
    float*          projPart = (float*)(ws + 53477376);         // [8,2048,256] 16.8 MB (pre-dtb)
    __hip_bfloat16* w_out_bf = (__hip_bfloat16*)(ws + 53477376); // after scan (dtb dead)
    // total 87.0 MB

    // 0. pre-cast to bf16
    cast_f32_bf16<<<2048, 256, 0, stream>>>(u, u_bf);
    cast_f32_bf16<<<8192, 256, 0, stream>>>(w_in, w_in_bf);

    // 1. weight concat
    build_wcat<<<4096, 256, 0, stream>>>(w_xdt, w_xb, w_xc, wcat);

    // 2. in_proj: xz = u @ w_in^T + b_in   (M=2048, N=8192, K=2048)
    gemm256_bt<<<dim3(32, 8), 512, 0, stream>>>(
        u_bf, 2048, w_in_bf, 2048, b_in, xz, 8192, 2048);

    // 3. conv + silu -> xc; silu(z) in place over xz z-half (z-gate)
    conv_siluz<<<8192, 256, 0, stream>>>(xz, xz, conv_w, conv_b, xc);

    // 4. proj = xc @ wcat^T, split-K=8      (M=2048, N=256, K=4096)
    gemm_bt_sk<<<dim3(2, 16, 8), 256, 0, stream>>>(
        xc, 4096, wcat, 4096, projPart, 256, 4096, 8, 524288);
    reduce_proj<<<2048, 256, 0, stream>>>(projPart, proj);

    // 5. cast w_dt (wcat region dead now)
    cast_f32_bf16<<<256, 256, 0, stream>>>(w_dt, w_dt_bf);

    // 6. dt = softplus(proj[:, :128] @ w_dt^T + b_dt)  (M=2048, N=4096, K=128)
    gemm_bt<1, float><<<dim3(32, 16), 256, 0, stream>>>(
        proj, 256, w_dt_bf, 128, b_dt, dtb, 4096, 128);

    // 7. selective scan -> yg (in-place over xc)
    scan_kernel<<<256, 256, 0, stream>>>(dtb, xc, proj, xz, A_log, D_par);

    // 8. cast w_out (dtb region dead now)
    cast_f32_bf16<<<4096, 256, 0, stream>>>(w_out, w_out_bf);

    // 9. out = yg @ w_out^T + b_out          (M=2048, N=2048, K=4096)
    gemm_bt<0, float><<<dim3(16, 16), 256, 0, stream>>>(
        xc, 4096, w_out_bf, 4096, b_out, out, 2048, 4096);
}

// Round 5
// 456.480 us; speedup vs baseline: 1.2158x; 1.2158x over previous
//
#include <hip/hip_runtime.h>
#include <hip/hip_bf16.h>

// UnifiedMambaBlock: B=2, L=1024, D_MODEL=2048, D_INNER=4096, N_STATE=16,
// DT_RANK=128, D_CONV=4.  ALL inputs/outputs fp32 (per reference dtypes).
// bf16 MFMA compute (no fp32 MFMA on CDNA4); fp32 epilogues.
//
// R12: dt GEMM FUSED INTO SCAN.  Profiling exposed the standalone dt GEMM
// (M=2048,N=4096,K=128 + softplus, fp32 out) at ~126us with 0.6% MfmaUtil --
// it wrote 33.5 MB dtb that the scan immediately re-read.  Now each scan
// block computes its own [128 t x 32 d] dt tile per chunk via MFMA from the
// staged proj chunk (s_pa) and w_dt rows (s_wd), straight into s_dt[d][t].
// Eliminates the dispatch + 67 MB of HBM round-trip.  softplus via fast
// v_exp/v_log builtins.
// R11: packed-FP32 scan (8 lanes/channel, f32x2 states), 32 ch/block.
// R10: z-gate silu(z) precomputed in conv kernel; conv vectorized.
// R8: in_proj GEMM = 256x256 deep-pipelined schedule.

#define DEV __device__ __forceinline__

typedef __attribute__((ext_vector_type(8))) __bf16 bf16x8;
typedef __attribute__((ext_vector_type(4))) float f32x4;
typedef __attribute__((ext_vector_type(2))) float f32x2;
typedef unsigned int u32;

DEV float bf2f(__hip_bfloat16 x) { return __bfloat162float(x); }
DEV __hip_bfloat16 f2bf(float x) { return __float2bfloat16(x); }
DEV float bfu2f(unsigned short u) {
    union { u32 i; float f; } c; c.i = ((u32)u) << 16; return c.f;
}
DEV unsigned short f2bfu(float x) {
    __hip_bfloat16 h = __float2bfloat16(x);
    return *reinterpret_cast<unsigned short*>(&h);
}
DEV float softplusf(float v) { return v > 20.f ? v : log1pf(__expf(v)); }
DEV float siluf(float v) { return v / (1.f + __expf(-v)); }
// fast softplus: ln(1+e^v) via v_exp_f32/v_log_f32 (log2-based).
DEV float softplus_fast(float v) {
    if (v > 20.f) return v;
    const float e = __builtin_amdgcn_exp2f(v * 1.44269504f);
    return 0.69314718f * __builtin_amdgcn_logf(1.f + e);
}

DEV void storeOut(float* C, size_t off, float v) { C[off] = v; }
DEV void storeOut(__hip_bfloat16* C, size_t off, float v) { C[off] = f2bf(v); }

// async 16B global -> LDS (global_load_lds_dwordx4).
// LDS destination must be wave-uniform base + lane*16 (HW constraint).
DEV void async16(void* lds, const void* g) {
    __builtin_amdgcn_global_load_lds(
        (const __attribute__((address_space(1))) u32*)(unsigned long long)g,
        (__attribute__((address_space(3))) u32*)(u32)(unsigned long long)lds,
        16, 0, 0);
}

// DPP-based add of lane (permuted) value; reduction over lane groups.
// MUST stay as the builtin: compiler inserts required DPP hazard nops.
template <int CTRL>
DEV float dppadd(float v) {
    int x = __builtin_amdgcn_update_dpp(
        0, __builtin_bit_cast(int, v), CTRL, 0xF, 0xF, true);
    return v + __builtin_bit_cast(float, x);
}

// ---------------------------------------------------------------------------
// 256x256-tile deep-pipelined GEMM: C = A @ W^T + bias (bf16 in, bf16 out).
// 512 threads = 8 waves (2M x 4N), per-wave 128x64 output, BK=32.
// 4 LDS buffers, prefetch distance 3 tiles, counted vmcnt, T2 swizzle, T5.
// Requires: M%256==0, N%256==0, K%32==0 (K>=96 for full pipeline benefit).
// ---------------------------------------------------------------------------
__global__ __launch_bounds__(512, 2) void gemm256_bt(
    const __hip_bfloat16* __restrict__ A, int lda,
    const __hip_bfloat16* __restrict__ W, int ldw,
    const float* __restrict__ bias,
    __hip_bfloat16* __restrict__ C, int ldc, int K)
{
    __shared__ __align__(16) unsigned short As[4][256 * 32];  // 64 KB
    __shared__ __align__(16) unsigned short Bs[4][256 * 32];  // 64 KB

    const int t    = threadIdx.x;
    // T1: bijective XCD swizzle (nwg % 8 == 0 guaranteed by launch shapes)
    const int nwg  = gridDim.x * gridDim.y;
    const int orig = blockIdx.y * gridDim.x + blockIdx.x;
    const int swz  = (orig & 7) * (nwg >> 3) + (orig >> 3);
    const int mBase = (swz / gridDim.x) * 256;
    const int nBase = (swz % gridDim.x) * 256;

    const int wave = t >> 6;
    const int lane = t & 63;
    const int wm   = (wave >> 2) * 128;   // 2 M wave-groups
    const int wn   = (wave & 3) * 64;     // 4 N wave-groups
    const int ln15 = lane & 15;
    const int quad = lane >> 4;
    const int kof  = quad * 8;

    f32x4 acc[8][4];
    const f32x4 vzero = {0.f, 0.f, 0.f, 0.f};
#pragma unroll
    for (int i = 0; i < 8; ++i)
#pragma unroll
        for (int j = 0; j < 4; ++j) acc[i][j] = vzero;

    // Stage one half-tile (rows half*128..half*128+127) of A and B of a
    // K-tile into buffer buf.  LDS dest is linear (HW constraint of
    // global_load_lds); the T2 swizzle is applied by INVERSE-swizzling the
    // global source address (rule #21).
    auto stage = [&](int buf, int k0, int half) {
        const int idx = half * 512 + t;                 // 0..1023 -> 16B slot
        const int le  = (idx * 8) ^ (((idx >> 3) & 3) << 3);
        const int r   = le >> 5;
        const int c   = le & 31;
        async16(&As[buf][idx * 8], A + (size_t)(mBase + r) * lda + k0 + c);
        async16(&Bs[buf][idx * 8], W + (size_t)(nBase + r) * ldw + k0 + c);
    };

    const int NT = K >> 5;

#pragma unroll 1
    for (int p = 0; p < 3 && p < NT; ++p) {
        stage(p, p << 5, 0);
        stage(p, p << 5, 1);
    }

#pragma unroll 1
    for (int T = 0; T < NT; ++T) {
        const int buf = T & 3;
        if (T + 2 < NT)      asm volatile("s_waitcnt vmcnt(8)" ::: "memory");
        else if (T + 1 < NT) asm volatile("s_waitcnt vmcnt(4)" ::: "memory");
        else                 asm volatile("s_waitcnt vmcnt(0)" ::: "memory");
        __builtin_amdgcn_s_barrier();          // all waves' vmcnt passed
        __builtin_amdgcn_sched_barrier(0);     // no ds_read hoists above

        const unsigned short* __restrict__ Ab = As[buf];
        const unsigned short* __restrict__ Bb = Bs[buf];
        const int k0n  = (T + 3) << 5;
        const int bufn = (T + 3) & 3;          // != buf; == (T-1)&3 (dead)

        // ---- phase 1: A-frags 0-3 + all B-frags, 16 MFMA ----
        bf16x8 af[4], bfr[4], af2[4];
#pragma unroll
        for (int i = 0; i < 4; ++i) {
            const int ra = wm + i * 16 + ln15;
            af[i] = *reinterpret_cast<const bf16x8*>(
                &Ab[(ra * 32 + kof) ^ (((ra >> 1) & 3) << 3)]);
            const int rb = wn + i * 16 + ln15;
            bfr[i] = *reinterpret_cast<const bf16x8*>(
                &Bb[(rb * 32 + kof) ^ (((rb >> 1) & 3) << 3)]);
        }
        if (T + 3 < NT) stage(bufn, k0n, 0);
        __builtin_amdgcn_s_barrier();
        __builtin_amdgcn_s_setprio(1);
#pragma unroll
        for (int i = 0; i < 4; ++i)
#pragma unroll
            for (int j = 0; j < 4; ++j)
                acc[i][j] = __builtin_amdgcn_mfma_f32_16x16x32_bf16(
                    af[i], bfr[j], acc[i][j], 0, 0, 0);
        __builtin_amdgcn_s_setprio(0);
        __builtin_amdgcn_sched_barrier(0);

        // ---- phase 2: A-frags 4-7 (reuse B-frags), 16 MFMA ----
#pragma unroll
        for (int i = 0; i < 4; ++i) {
            const int ra = wm + 64 + i * 16 + ln15;
            af2[i] = *reinterpret_cast<const bf16x8*>(
                &Ab[(ra * 32 + kof) ^ (((ra >> 1) & 3) << 3)]);
        }
        if (T + 3 < NT) stage(bufn, k0n, 1);
        __builtin_amdgcn_s_barrier();
        __builtin_amdgcn_s_setprio(1);
#pragma unroll
        for (int i = 0; i < 4; ++i)
#pragma unroll
            for (int j = 0; j < 4; ++j)
                acc[4 + i][j] = __builtin_amdgcn_mfma_f32_16x16x32_bf16(
                    af2[i], bfr[j], acc[4 + i][j], 0, 0, 0);
        __builtin_amdgcn_s_setprio(0);
        __builtin_amdgcn_sched_barrier(0);
    }

    // epilogue: C/D layout col = lane&15, row = quad*4 + reg
#pragma unroll
    for (int i = 0; i < 8; ++i) {
        const int gm = mBase + wm + i * 16 + quad * 4;
#pragma unroll
        for (int j = 0; j < 4; ++j) {
            const int gn = nBase + wn + j * 16 + ln15;
            const float bv = bias ? bias[gn] : 0.f;
#pragma unroll
            for (int r = 0; r < 4; ++r)
                C[(size_t)(gm + r) * ldc + gn] = f2bf(acc[i][j][r] + bv);
        }
    }
}

// ---------------------------------------------------------------------------
// C = A @ W^T + bias GEMM, bf16 inputs, DOUBLE-BUFFERED async LDS staging.
// Block tile 128x128, BK=64, 256 threads = 4 waves 2x2, wave does 64x64 via
// 4x4 frags of mfma_f32_16x16x32_bf16.
// Requires: M%128==0, N%128==0, K%64==0, lda/ldw mult of 8.
// ---------------------------------------------------------------------------
template <int ACT, typename OutT>
__global__ __launch_bounds__(256) void gemm_bt(
    const __hip_bfloat16* __restrict__ A, int lda,
    const __hip_bfloat16* __restrict__ W, int ldw,
    const float* __restrict__ bias,
    OutT* __restrict__ C, int ldc, int K)
{
    __shared__ __align__(16) unsigned short AsU[2][128 * 64];
    __shared__ __align__(16) unsigned short BsU[2][128 * 64];

    const int t     = threadIdx.x;
    const int mBase = blockIdx.y * 128;
    const int nBase = blockIdx.x * 128;
    const int wave  = t >> 6;
    const int lane  = t & 63;
    const int wm    = (wave >> 1) * 64;
    const int wn    = (wave & 1) * 64;
    const int ln15  = lane & 15;
    const int quad  = lane >> 4;

    f32x4 acc[4][4];
    const f32x4 vzero = {0.f, 0.f, 0.f, 0.f};
#pragma unroll
    for (int i = 0; i < 4; ++i)
#pragma unroll
        for (int j = 0; j < 4; ++j) acc[i][j] = vzero;

    auto stage = [&](int buf, int k0) {
#pragma unroll
        for (int i = 0; i < 4; ++i) {
            int idx = i * 256 + t;
            int r = idx >> 3;
            int c = (idx & 7) << 3;
            async16(&AsU[buf][idx * 8], A + (size_t)(mBase + r) * lda + k0 + c);
            async16(&BsU[buf][idx * 8], W + (size_t)(nBase + r) * ldw + k0 + c);
        }
    };

    const int nIter = K >> 6;
    stage(0, 0);

    for (int it = 0; it < nIter; ++it) {
        __syncthreads();   // buf[it&1] resident; prior reads of other buf done
        if (it + 1 < nIter) stage((it + 1) & 1, (it + 1) << 6);
        const unsigned short* As = AsU[it & 1];
        const unsigned short* Bs = BsU[it & 1];

#pragma unroll
        for (int kk = 0; kk < 64; kk += 32) {
            const int kof = kk + quad * 8;
            bf16x8 af[4], bfr[4];
#pragma unroll
            for (int i = 0; i < 4; ++i) {
                af[i]  = *reinterpret_cast<const bf16x8*>(&As[(wm + i * 16 + ln15) * 64 + kof]);
                bfr[i] = *reinterpret_cast<const bf16x8*>(&Bs[(wn + i * 16 + ln15) * 64 + kof]);
            }
#pragma unroll
            for (int i = 0; i < 4; ++i)
#pragma unroll
                for (int j = 0; j < 4; ++j)
                    acc[i][j] = __builtin_amdgcn_mfma_f32_16x16x32_bf16(af[i], bfr[j], acc[i][j], 0, 0, 0);
        }
    }

    // epilogue: C/D layout col = lane&15, row = quad*4 + reg
#pragma unroll
    for (int i = 0; i < 4; ++i) {
        const int gm = mBase + wm + i * 16 + quad * 4;
#pragma unroll
        for (int j = 0; j < 4; ++j) {
            const int gn = nBase + wn + j * 16 + ln15;
            const float bv = bias ? bias[gn] : 0.f;
#pragma unroll
            for (int r = 0; r < 4; ++r) {
                float v = acc[i][j][r] + bv;
                if (ACT == 1) v = softplusf(v);
                storeOut(C, (size_t)(gm + r) * ldc + gn, v);
            }
        }
    }
}

// ---------------------------------------------------------------------------
// Split-K variant: grid (nx, ny, SLICES); slice z handles K-range
// [z*K/SLICES, (z+1)*K/SLICES), stores fp32 partial at part + z*sliceElems.
// ---------------------------------------------------------------------------
__global__ __launch_bounds__(256) void gemm_bt_sk(
    const __hip_bfloat16* __restrict__ A, int lda,
    const __hip_bfloat16* __restrict__ W, int ldw,
    float* __restrict__ part, int ldc, int K, int slices, int sliceElems)
{
    __shared__ __align__(16) unsigned short AsU[2][128 * 64];
    __shared__ __align__(16) unsigned short BsU[2][128 * 64];

    const int t     = threadIdx.x;
    const int mBase = blockIdx.y * 128;
    const int nBase = blockIdx.x * 128;
    const int kLen  = K / slices;
    const int kOff  = blockIdx.z * kLen;
    const int wave  = t >> 6;
    const int lane  = t & 63;
    const int wm    = (wave >> 1) * 64;
    const int wn    = (wave & 1) * 64;
    const int ln15  = lane & 15;
    const int quad  = lane >> 4;

    f32x4 acc[4][4];
    const f32x4 vzero = {0.f, 0.f, 0.f, 0.f};
#pragma unroll
    for (int i = 0; i < 4; ++i)
#pragma unroll
        for (int j = 0; j < 4; ++j) acc[i][j] = vzero;

    auto stage = [&](int buf, int k0) {
#pragma unroll
        for (int i = 0; i < 4; ++i) {
            int idx = i * 256 + t;
            int r = idx >> 3;
            int c = (idx & 7) << 3;
            async16(&AsU[buf][idx * 8], A + (size_t)(mBase + r) * lda + k0 + c);
            async16(&BsU[buf][idx * 8], W + (size_t)(nBase + r) * ldw + k0 + c);
        }
    };

    const int nIter = kLen >> 6;
    stage(0, kOff);

    for (int it = 0; it < nIter; ++it) {
        __syncthreads();
        if (it + 1 < nIter) stage((it + 1) & 1, kOff + ((it + 1) << 6));
        const unsigned short* As = AsU[it & 1];
        const unsigned short* Bs = BsU[it & 1];

#pragma unroll
        for (int kk = 0; kk < 64; kk += 32) {
            const int kof = kk + quad * 8;
            bf16x8 af[4], bfr[4];
#pragma unroll
            for (int i = 0; i < 4; ++i) {
                af[i]  = *reinterpret_cast<const bf16x8*>(&As[(wm + i * 16 + ln15) * 64 + kof]);
                bfr[i] = *reinterpret_cast<const bf16x8*>(&Bs[(wn + i * 16 + ln15) * 64 + kof]);
            }
#pragma unroll
            for (int i = 0; i < 4; ++i)
#pragma unroll
                for (int j = 0; j < 4; ++j)
                    acc[i][j] = __builtin_amdgcn_mfma_f32_16x16x32_bf16(af[i], bfr[j], acc[i][j], 0, 0, 0);
        }
    }

    float* Cp = part + (size_t)blockIdx.z * sliceElems;
#pragma unroll
    for (int i = 0; i < 4; ++i) {
        const int gm = mBase + wm + i * 16 + quad * 4;
#pragma unroll
        for (int j = 0; j < 4; ++j) {
            const int gn = nBase + wn + j * 16 + ln15;
#pragma unroll
            for (int r = 0; r < 4; ++r)
                Cp[(size_t)(gm + r) * ldc + gn] = acc[i][j][r];
        }
    }
}

// sum 8 fp32 partials -> bf16 proj.  total = 2048*256 elems.
__global__ __launch_bounds__(256) void reduce_proj(
    const float* __restrict__ part, __hip_bfloat16* __restrict__ proj)
{
    int i = blockIdx.x * 256 + threadIdx.x;
    float s = 0.f;
#pragma unroll
    for (int z = 0; z < 8; ++z) s += part[(size_t)z * 524288 + i];
    proj[i] = f2bf(s);
}

// ---------------------------------------------------------------------------
// fp32 -> bf16 cast, 8 elems/thread.  n must be a multiple of 2048.
// ---------------------------------------------------------------------------
__global__ __launch_bounds__(256) void cast_f32_bf16(
    const float* __restrict__ in, __hip_bfloat16* __restrict__ out)
{
    size_t i = ((size_t)blockIdx.x * 256 + threadIdx.x) * 8;
    const float4 a = *reinterpret_cast<const float4*>(in + i);
    const float4 b = *reinterpret_cast<const float4*>(in + i + 4);
    unsigned short r[8];
    r[0] = f2bfu(a.x); r[1] = f2bfu(a.y); r[2] = f2bfu(a.z); r[3] = f2bfu(a.w);
    r[4] = f2bfu(b.x); r[5] = f2bfu(b.y); r[6] = f2bfu(b.z); r[7] = f2bfu(b.w);
    *reinterpret_cast<uint4*>(out + i) = *reinterpret_cast<uint4*>(r);
}

// ---------------------------------------------------------------------------
// wcat bf16 [256,4096]: rows 0..127 w_xdt, 128..143 w_xb, 144..159 w_xc.
// ---------------------------------------------------------------------------
__global__ __launch_bounds__(256) void build_wcat(
    const float* __restrict__ w_xdt,
    const float* __restrict__ w_xb,
    const float* __restrict__ w_xc,
    __hip_bfloat16* __restrict__ wcat)
{
    int tid = blockIdx.x * 256 + threadIdx.x;
    int r = tid >> 12;
    int c = tid & 4095;
    float v = 0.f;
    if (r < 128)      v = w_xdt[r * 4096 + c];
    else if (r < 144) v = w_xb[(r - 128) * 4096 + c];
    else if (r < 160) v = w_xc[(r - 144) * 4096 + c];
    wcat[tid] = f2bf(v);
}

// ---------------------------------------------------------------------------
// Vectorized causal depthwise conv (win 4, left pad 3) + bias + silu over
// xz[:, :4096] -> xc, AND silu over xz[:, 4096:] IN PLACE (z-gate precompute
// for the scan).  8 outputs per thread, uint4 loads/stores.
// ---------------------------------------------------------------------------
__global__ __launch_bounds__(256) void conv_siluz(
    const __hip_bfloat16* __restrict__ xzr,
    __hip_bfloat16* __restrict__ xzw,          // same buffer, z-half writes
    const float* __restrict__ conv_w,
    const float* __restrict__ conv_b,
    __hip_bfloat16* __restrict__ xc)
{
    const int tid = blockIdx.x * 256 + threadIdx.x;
    if (tid < (1 << 20)) {
        const int row = tid >> 9;            // 0..2047 (b*1024 + l)
        const int d8  = (tid & 511) << 3;    // 0..4088 step 8
        const int l   = row & 1023;
        uint4 tv[4];
#pragma unroll
        for (int k = 0; k < 4; ++k) {
            const int ll = l - 3 + k;
            if (ll >= 0)
                tv[k] = *reinterpret_cast<const uint4*>(
                    &xzr[(size_t)(row - 3 + k) * 8192 + d8]);
            else
                tv[k] = make_uint4(0u, 0u, 0u, 0u);   // bf16 zeros
        }
        const float4 b0 = *reinterpret_cast<const float4*>(&conv_b[d8]);
        const float4 b1 = *reinterpret_cast<const float4*>(&conv_b[d8 + 4]);
        const unsigned short* t0 = (const unsigned short*)&tv[0];
        const unsigned short* t1 = (const unsigned short*)&tv[1];
        const unsigned short* t2 = (const unsigned short*)&tv[2];
        const unsigned short* t3 = (const unsigned short*)&tv[3];
        unsigned short o[8];
#pragma unroll
        for (int j = 0; j < 8; ++j) {
            const float4 w = *reinterpret_cast<const float4*>(&conv_w[(d8 + j) * 4]);
            float acc = (j < 4) ? ((const float*)&b0)[j] : ((const float*)&b1)[j - 4];
            acc += bfu2f(t0[j]) * w.x;
            acc += bfu2f(t1[j]) * w.y;
            acc += bfu2f(t2[j]) * w.z;
            acc += bfu2f(t3[j]) * w.w;
            o[j] = f2bfu(siluf(acc));
        }
        *reinterpret_cast<uint4*>(&xc[(size_t)row * 4096 + d8]) =
            *reinterpret_cast<const uint4*>(o);
    } else {
        const int zi  = tid - (1 << 20);
        const int row = zi >> 9;
        const int d8  = (zi & 511) << 3;
        const size_t a = (size_t)row * 8192 + 4096 + d8;
        const uint4 v = *reinterpret_cast<const uint4*>(&xzr[a]);
        const unsigned short* zv = (const unsigned short*)&v;
        unsigned short o[8];
#pragma unroll
        for (int j = 0; j < 8; ++j)
            o[j] = f2bfu(siluf(bfu2f(zv[j])));
        *reinterpret_cast<uint4*>(&xzw[a]) = *reinterpret_cast<const uint4*>(o);
    }
}

// ---------------------------------------------------------------------------
// selective scan with FUSED dt computation.  Packed-FP32: 8 lanes/channel
// (n0 = t&7), states (n0, n0+8) as f32x2.  32 channels/block, 256 blocks.
// Per chunk (128 t): stage proj[:, :128] chunk into s_pa (XOR-swizzled via
// pre-swizzled async16 source), MFMA [128t x 32d] dt-tile against s_wd
// (w_dt rows), softplus, write s_dt[d][t]; then run the scan.
// z-half of xz holds PRE-GATED silu(z).
// ---------------------------------------------------------------------------
#define SCAN_T 128
#define ST4 132
#define ST2 136

__global__ __launch_bounds__(256) void scan_kernel(
    const __hip_bfloat16* __restrict__ proj,   // [2048,256]; dt-K at 0, B at 128, C at 144
    __hip_bfloat16* xcyg,                      // [2048, 4096] bf16 in/out
    const __hip_bfloat16* __restrict__ xz,     // [2048, 8192]; zg at 4096+d
    const __hip_bfloat16* __restrict__ wdt,    // [4096, 128] bf16
    const float* __restrict__ bdt,             // [4096] fp32
    const float* __restrict__ A_log,           // [4096, 16] fp32
    const float* __restrict__ Dp)              // [4096] fp32
{
    __shared__ __align__(16) float          s_dt[32 * ST4];   // [d][time]
    __shared__ __align__(16) unsigned short s_x [32 * ST2];
    __shared__ __align__(16) unsigned short s_z [32 * ST2];
    __shared__ __align__(16) unsigned short s_B [16 * ST2];   // [state][time]
    __shared__ __align__(16) unsigned short s_C [16 * ST2];
    __shared__ __align__(16) unsigned short s_y [32 * ST2];
    __shared__ __align__(16) unsigned short s_pa[128 * 128];  // proj chunk [t][k], swz
    __shared__ __align__(16) unsigned short s_wd[32 * 128];   // w_dt [d][k], swz

    const int t    = threadIdx.x;
    const int g    = t >> 3;         // channel in block, 0..31
    const int n0   = t & 7;          // state pair base (n0, n0+8)
    const int wave = t >> 6;
    const int lane = t & 63;
    const int ln15 = lane & 15;
    const int quad = lane >> 4;
    const int wm32 = wave * 32;      // wave's 32-row t-stripe of the dt tile
    const int ch0  = blockIdx.x * 32;
    const int b    = ch0 >> 12;
    const int d0   = ch0 & 4095;
    const int d    = d0 + g;

    f32x2 A2;
    A2.x = -__expf(A_log[d * 16 + n0]) * 1.44269504f;
    A2.y = -__expf(A_log[d * 16 + n0 + 8]) * 1.44269504f;
    const float Dpar = Dp[d];
    const size_t rowBase = (size_t)b * 1024;
    // b_dt values for this lane's two d-columns of the dt tile
    float bdtv[2];
#pragma unroll
    for (int j = 0; j < 2; ++j) bdtv[j] = bdt[d0 + j * 16 + ln15];

    // stage w_dt rows d0..d0+31 once (XOR-swizzled source, linear LDS dest)
#pragma unroll
    for (int s = 0; s < 2; ++s) {
        const int idx = s * 256 + t;
        const int le  = (idx * 8) ^ (((idx >> 4) & 7) << 3);
        async16(&s_wd[idx * 8], &wdt[(size_t)(d0 + (idx >> 4)) * 128 + (le & 127)]);
    }

    // staging thread mappings (128 time-rows per chunk)
    const int rX = t >> 2, cX = (t & 3) << 3;   // x/z/y: rows rX+64i, 8 shorts
    const int rB = t >> 1, cB = (t & 1) << 3;   // B/C: row rB, 8 shorts

    uint4 rx[2], rz[2], rBv, rCv;
    auto load_chunk = [&](int t0) {
#pragma unroll
        for (int i = 0; i < 2; ++i) {
            rx[i] = *reinterpret_cast<const uint4*>(
                &xcyg[(rowBase + t0 + rX + i * 64) * 4096 + d0 + cX]);
            rz[i] = *reinterpret_cast<const uint4*>(
                &xz[(rowBase + t0 + rX + i * 64) * 8192 + 4096 + d0 + cX]);
        }
        rBv = *reinterpret_cast<const uint4*>(
            &proj[(rowBase + t0 + rB) * 256 + 128 + cB]);
        rCv = *reinterpret_cast<const uint4*>(
            &proj[(rowBase + t0 + rB) * 256 + 144 + cB]);
    };

    load_chunk(0);
    f32x2 h = {0.f, 0.f};

#pragma unroll 1
    for (int c = 0; c < 1024 / SCAN_T; ++c) {
        const int t0 = c * SCAN_T;
        __syncthreads();                 // prior chunk's LDS reads complete

        // stage proj chunk rows t0..t0+127, cols 0..127 (async -> s_pa)
#pragma unroll
        for (int s = 0; s < 8; ++s) {
            const int idx = s * 256 + t;
            const int le  = (idx * 8) ^ (((idx >> 4) & 7) << 3);
            async16(&s_pa[idx * 8],
                    &proj[(rowBase + t0 + (idx >> 4)) * 256 + (le & 127)]);
        }
        // write prefetched x/z/B/C regs into LDS
        {
#pragma unroll
            for (int i = 0; i < 2; ++i) {
                const unsigned short* px = (const unsigned short*)&rx[i];
                const unsigned short* pz = (const unsigned short*)&rz[i];
#pragma unroll
                for (int jj = 0; jj < 8; ++jj) {
                    s_x[(cX + jj) * ST2 + rX + i * 64] = px[jj];
                    s_z[(cX + jj) * ST2 + rX + i * 64] = pz[jj];
                }
            }
            const unsigned short* pB = (const unsigned short*)&rBv;
            const unsigned short* pC = (const unsigned short*)&rCv;
#pragma unroll
            for (int jj = 0; jj < 8; ++jj) {
                s_B[(cB + jj) * ST2 + rB] = pB[jj];
                s_C[(cB + jj) * ST2 + rB] = pC[jj];
            }
        }
        __syncthreads();                 // drains vmcnt: s_pa/s_wd resident
        if (c + 1 < 1024 / SCAN_T) load_chunk(t0 + SCAN_T);

        // ---- fused dt tile: [128 t x 32 d] = softplus(projK @ wdt^T + bdt)
        {
            f32x4 dacc[2][2];
            const f32x4 vz4 = {0.f, 0.f, 0.f, 0.f};
#pragma unroll
            for (int i = 0; i < 2; ++i)
#pragma unroll
                for (int j = 0; j < 2; ++j) dacc[i][j] = vz4;
#pragma unroll
            for (int ks = 0; ks < 4; ++ks) {
                const int kof = ks * 32 + quad * 8;
                bf16x8 paf[2], wbf[2];
#pragma unroll
                for (int i = 0; i < 2; ++i) {
                    const int ra = wm32 + i * 16 + ln15;
                    paf[i] = *reinterpret_cast<const bf16x8*>(
                        &s_pa[(ra * 128 + kof) ^ ((ra & 7) << 3)]);
                    const int rb = i * 16 + ln15;
                    wbf[i] = *reinterpret_cast<const bf16x8*>(
                        &s_wd[(rb * 128 + kof) ^ ((rb & 7) << 3)]);
                }
#pragma unroll
                for (int i = 0; i < 2; ++i)
#pragma unroll
                    for (int j = 0; j < 2; ++j)
                        dacc[i][j] = __builtin_amdgcn_mfma_f32_16x16x32_bf16(
                            paf[i], wbf[j], dacc[i][j], 0, 0, 0);
            }
            // epilogue: C[m=t, n=d]; col=ln15, row=quad*4+r -> s_dt[d][t]
#pragma unroll
            for (int i = 0; i < 2; ++i) {
                const int tb = wm32 + i * 16 + quad * 4;
#pragma unroll
                for (int j = 0; j < 2; ++j) {
                    const int dd = j * 16 + ln15;
                    f32x4 w;
#pragma unroll
                    for (int r = 0; r < 4; ++r)
                        w[r] = softplus_fast(dacc[i][j][r] + bdtv[j]);
                    *reinterpret_cast<f32x4*>(&s_dt[dd * ST4 + tb]) = w;
                }
            }
        }
        __syncthreads();                 // s_dt visible to all waves

#pragma unroll 1
        for (int l0 = 0; l0 < SCAN_T; l0 += 8) {
            const float4 vd0 = *reinterpret_cast<const float4*>(&s_dt[g * ST4 + l0]);
            const float4 vd1 = *reinterpret_cast<const float4*>(&s_dt[g * ST4 + l0 + 4]);
            const uint4 vx  = *reinterpret_cast<const uint4*>(&s_x[g * ST2 + l0]);
            const uint4 vz  = *reinterpret_cast<const uint4*>(&s_z[g * ST2 + l0]);
            const uint4 vB0 = *reinterpret_cast<const uint4*>(&s_B[n0 * ST2 + l0]);
            const uint4 vB1 = *reinterpret_cast<const uint4*>(&s_B[(n0 + 8) * ST2 + l0]);
            const uint4 vC0 = *reinterpret_cast<const uint4*>(&s_C[n0 * ST2 + l0]);
            const uint4 vC1 = *reinterpret_cast<const uint4*>(&s_C[(n0 + 8) * ST2 + l0]);
            const unsigned short* ux  = (const unsigned short*)&vx;
            const unsigned short* uz  = (const unsigned short*)&vz;
            const unsigned short* uB0 = (const unsigned short*)&vB0;
            const unsigned short* uB1 = (const unsigned short*)&vB1;
            const unsigned short* uC0 = (const unsigned short*)&vC0;
            const unsigned short* uC1 = (const unsigned short*)&vC1;
            const float* fd0 = (const float*)&vd0;
            const float* fd1 = (const float*)&vd1;
            unsigned short y8[8];
#pragma unroll
            for (int j = 0; j < 8; ++j) {
                const float dtv = (j < 4) ? fd0[j] : fd1[j - 4];
                const float xv  = bfu2f(ux[j]);
                f32x2 Bp; Bp.x = bfu2f(uB0[j]); Bp.y = bfu2f(uB1[j]);
                f32x2 Cp; Cp.x = bfu2f(uC0[j]); Cp.y = bfu2f(uC1[j]);
                const f32x2 dA = A2 * (f32x2){dtv, dtv};
                f32x2 e;
                e.x = __builtin_amdgcn_exp2f(dA.x);
                e.y = __builtin_amdgcn_exp2f(dA.y);
                const float xdt = xv * dtv;
                const f32x2 tt = Bp * (f32x2){xdt, xdt};
                h = __builtin_elementwise_fma(h, e, tt);   // v_pk_fma_f32
                const f32x2 pp = h * Cp;
                float p = pp.x + pp.y;
                p = dppadd<0xB1>(p);    // xor1 within quad
                p = dppadd<0x4E>(p);    // xor2 within quad
                p = dppadd<0x141>(p);   // half-row mirror: combine quads
                if (n0 == 0) {
                    const float zgv = bfu2f(uz[j]);   // pre-gated silu(z)
                    y8[j] = f2bfu((p + Dpar * xv) * zgv);
                }
            }
            if (n0 == 0)
                *reinterpret_cast<uint4*>(&s_y[g * ST2 + l0]) =
                    *reinterpret_cast<const uint4*>(y8);
        }
        __syncthreads();

        {
#pragma unroll
            for (int i = 0; i < 2; ++i) {
                unsigned short tmp[8];
#pragma unroll
                for (int jj = 0; jj < 8; ++jj)
                    tmp[jj] = s_y[(cX + jj) * ST2 + rX + i * 64];
                *reinterpret_cast<uint4*>(
                    &xcyg[(rowBase + t0 + rX + i * 64) * 4096 + d0 + cX]) =
                    *reinterpret_cast<const uint4*>(tmp);
            }
        }
    }
}

// ---------------------------------------------------------------------------
extern "C" void kernel_launch(void* const* d_in, const int* in_sizes, int n_in,
                              void* d_out, int out_size, void* d_ws, size_t ws_size,
                              hipStream_t stream)
{
    const float* u      = (const float*)d_in[0];
    const float* w_in   = (const float*)d_in[1];
    const float* b_in   = (const float*)d_in[2];
    const float* w_out  = (const float*)d_in[3];
    const float* b_out  = (const float*)d_in[4];
    const float* w_dt   = (const float*)d_in[5];
    const float* b_dt   = (const float*)d_in[6];
    const float* w_xdt  = (const float*)d_in[7];
    const float* w_xb   = (const float*)d_in[8];
    const float* w_xc   = (const float*)d_in[9];
    const float* conv_w = (const float*)d_in[10];
    const float* conv_b = (const float*)d_in[11];
    const float* A_log  = (const float*)d_in[12];
    const float* D_par  = (const float*)d_in[13];
    float* out = (float*)d_out;

    char* ws = (char*)d_ws;
    __hip_bfloat16* xz    = (__hip_bfloat16*)(ws);             // [2048,8192] 33.5 MB
    __hip_bfloat16* xc    = (__hip_bfloat16*)(ws + 33554432);  // [2048,4096] 16.8 MB
    __hip_bfloat16* u_bf  = (__hip_bfloat16*)(ws + 33554432);  // dead before xc written
    __hip_bfloat16* wcat  = (__hip_bfloat16*)(ws + 50331648);  // [256,4096]  2.1 MB
    __hip_bfloat16* w_dt_bf = (__hip_bfloat16*)(ws + 50331648);// [4096,128] 1 MB (after wcat dead)
    __hip_bfloat16* proj  = (__hip_bfloat16*)(ws + 52428800);  // [2048,256]  1.0 MB
    __hip_bfloat16* w_in_bf  = (__hip_bfloat16*)(ws + 53477376); // [8192,2048] bf16 33.5MB
    float*          projPart = (float*)(ws + 53477376);         // [8,2048,256] 16.8 MB (after w_in_bf dead)
    __hip_bfloat16* w_out_bf = (__hip_bfloat16*)(ws + 53477376); // after scan
    // total 87.0 MB

    // 0. pre-cast to bf16
    cast_f32_bf16<<<2048, 256, 0, stream>>>(u, u_bf);
    cast_f32_bf16<<<8192, 256, 0, stream>>>(w_in, w_in_bf);

    // 1. weight concat
    build_wcat<<<4096, 256, 0, stream>>>(w_xdt, w_xb, w_xc, wcat);

    // 2. in_proj: xz = u @ w_in^T + b_in   (M=2048, N=8192, K=2048)
    gemm256_bt<<<dim3(32, 8), 512, 0, stream>>>(
        u_bf, 2048, w_in_bf, 2048, b_in, xz, 8192, 2048);

    // 3. conv + silu -> xc; silu(z) in place over xz z-half (z-gate)
    conv_siluz<<<8192, 256, 0, stream>>>(xz, xz, conv_w, conv_b, xc);

    // 4. proj = xc @ wcat^T, split-K=8      (M=2048, N=256, K=4096)
    gemm_bt_sk<<<dim3(2, 16, 8), 256, 0, stream>>>(
        xc, 4096, wcat, 4096, projPart, 256, 4096, 8, 524288);
    reduce_proj<<<2048, 256, 0, stream>>>(projPart, proj);

    // 5. cast w_dt (wcat region dead now)
    cast_f32_bf16<<<256, 256, 0, stream>>>(w_dt, w_dt_bf);

    // 6+7. selective scan with FUSED dt GEMM -> yg (in-place over xc)
    scan_kernel<<<256, 256, 0, stream>>>(
        proj, xc, xz, w_dt_bf, b_dt, A_log, D_par);

    // 8. cast w_out (projPart region dead now)
    cast_f32_bf16<<<4096, 256, 0, stream>>>(w_out, w_out_bf);

    // 9. out = yg @ w_out^T + b_out          (M=2048, N=2048, K=4096)
    gemm_bt<0, float><<<dim3(16, 16), 256, 0, stream>>>(
        xc, 4096, w_out_bf, 4096, b_out, out, 2048, 4096);
}